// Round 3
// baseline (582.621 us; speedup 1.0000x reference)
//
#include <hip/hip_runtime.h>

// ---------------- degree / CSR construction ----------------

__global__ void count_k(const int* __restrict__ dst, int* __restrict__ cnt, int E) {
    int e = blockIdx.x * blockDim.x + threadIdx.x;
    if (e < E) atomicAdd(&cnt[dst[e]], 1);
}

__global__ void dinv_k(const int* __restrict__ cnt, float* __restrict__ dinv, int N) {
    int i = blockIdx.x * blockDim.x + threadIdx.x;
    if (i < N) dinv[i] = rsqrtf((float)cnt[i] + 1.0f);
}

__global__ void scan1(const int* __restrict__ cnt, int* __restrict__ incl,
                      int* __restrict__ bsum, int n) {
    __shared__ int tmp[256];
    int t = threadIdx.x;
    int gid = blockIdx.x * 256 + t;
    tmp[t] = (gid < n) ? cnt[gid] : 0;
    __syncthreads();
    for (int off = 1; off < 256; off <<= 1) {
        int v = (t >= off) ? tmp[t - off] : 0;
        __syncthreads();
        tmp[t] += v;
        __syncthreads();
    }
    if (gid < n) incl[gid] = tmp[t];
    if (t == 255) bsum[blockIdx.x] = tmp[255];
}

__global__ void scan2(const int* __restrict__ bsum, int* __restrict__ boff, int nb) {
    __shared__ int tmp[512];
    int t = threadIdx.x;
    int orig = (t < nb) ? bsum[t] : 0;
    tmp[t] = orig;
    __syncthreads();
    for (int off = 1; off < 512; off <<= 1) {
        int v = (t >= off) ? tmp[t - off] : 0;
        __syncthreads();
        tmp[t] += v;
        __syncthreads();
    }
    if (t < nb) boff[t] = tmp[t] - orig;   // exclusive block offset
}

__global__ void scan3(const int* __restrict__ incl, const int* __restrict__ boff,
                      int* __restrict__ rowptr, int* __restrict__ cursor, int n) {
    int i = blockIdx.x * 256 + threadIdx.x;
    if (i < n) {
        int v = incl[i] + boff[blockIdx.x];
        rowptr[i + 1] = v;
        cursor[i + 1] = v;
    }
    if (i == 0) { rowptr[0] = 0; cursor[0] = 0; }
}

// cursor pre-seeded to rowptr: atomicAdd returns the global slot directly
__global__ void scatter_k(const int* __restrict__ src, const int* __restrict__ dst,
                          int* __restrict__ cursor, int* __restrict__ col, int E) {
    int e = blockIdx.x * blockDim.x + threadIdx.x;
    if (e >= E) return;
    int d = dst[e];
    int p = atomicAdd(&cursor[d], 1);
    col[p] = src[e];
}

// ---------------- GEMM: G = (X @ W) * dinv[row], 128x128 tile, 8x8 reg block ----

__global__ __launch_bounds__(256) void gemm128(const float* __restrict__ X,
                                               const float* __restrict__ W,
                                               const float* __restrict__ dinv,
                                               float* __restrict__ G, int M) {
    __shared__ float Xs[32][132];   // transposed [kk][row], padded
    __shared__ float Ws[32][128];   // [kk][col]
    int row0 = blockIdx.x * 128;
    int t = threadIdx.x;
    int tx = t & 15, ty = t >> 4;
    int c0 = tx * 8, r0 = ty * 8;
    float acc[8][8];
#pragma unroll
    for (int i = 0; i < 8; ++i)
#pragma unroll
        for (int j = 0; j < 8; ++j) acc[i][j] = 0.f;

    int lr = t & 7;
    int rbase = t >> 3;

    for (int k0 = 0; k0 < 128; k0 += 32) {
#pragma unroll
        for (int p = 0; p < 4; ++p) {
            int r = rbase + p * 32;
            int rr = row0 + r; if (rr >= M) rr = M - 1;
            const float4 v = *(const float4*)&X[(size_t)rr * 128 + k0 + lr * 4];
            Xs[lr * 4 + 0][r] = v.x;
            Xs[lr * 4 + 1][r] = v.y;
            Xs[lr * 4 + 2][r] = v.z;
            Xs[lr * 4 + 3][r] = v.w;
        }
#pragma unroll
        for (int p = 0; p < 4; ++p) {
            int cc = lr * 4 + p * 32;
            *(float4*)&Ws[rbase][cc] = *(const float4*)&W[(size_t)(k0 + rbase) * 128 + cc];
        }
        __syncthreads();
#pragma unroll
        for (int kk = 0; kk < 32; ++kk) {
            float xa[8], wb[8];
            *(float4*)&xa[0] = *(const float4*)&Xs[kk][r0];
            *(float4*)&xa[4] = *(const float4*)&Xs[kk][r0 + 4];
            *(float4*)&wb[0] = *(const float4*)&Ws[kk][c0];
            *(float4*)&wb[4] = *(const float4*)&Ws[kk][c0 + 4];
#pragma unroll
            for (int i = 0; i < 8; ++i)
#pragma unroll
                for (int j = 0; j < 8; ++j)
                    acc[i][j] += xa[i] * wb[j];
        }
        __syncthreads();
    }
#pragma unroll
    for (int i = 0; i < 8; ++i) {
        int row = row0 + r0 + i;
        if (row < M) {
            float di = dinv[row];
            float4 o0, o1;
            o0.x = acc[i][0] * di; o0.y = acc[i][1] * di;
            o0.z = acc[i][2] * di; o0.w = acc[i][3] * di;
            o1.x = acc[i][4] * di; o1.y = acc[i][5] * di;
            o1.z = acc[i][6] * di; o1.w = acc[i][7] * di;
            *(float4*)&G[(size_t)row * 128 + c0]     = o0;
            *(float4*)&G[(size_t)row * 128 + c0 + 4] = o1;
        }
    }
}

// ------- aggregation (128-dim): wave per node, float4 lanes, 2 edge slots ------
// Out[n] = dinv[n] * (sum_e G[col[e]] + G[n]) + bias, optional relu

__global__ __launch_bounds__(256) void aggregate128(const float4* __restrict__ G4,
                                                    const float* __restrict__ dinv,
                                                    const int* __restrict__ rowptr,
                                                    const int* __restrict__ col,
                                                    const float4* __restrict__ bias4,
                                                    float4* __restrict__ Out4,
                                                    int relu, int N) {
    int n = blockIdx.x * 4 + (threadIdx.x >> 6);
    if (n >= N) return;
    int lane = threadIdx.x & 63;
    int f = lane & 31;        // float4 index within row
    int slot = lane >> 5;     // which edge of the pair
    int e0 = rowptr[n], e1 = rowptr[n + 1];
    float4 acc = make_float4(0.f, 0.f, 0.f, 0.f);

    int base = e0;
    for (; base + 8 <= e1; base += 8) {
        int i0 = base + slot;
        int s0 = col[i0], s1 = col[i0 + 2], s2 = col[i0 + 4], s3 = col[i0 + 6];
        float4 v0 = G4[(size_t)s0 * 32 + f];
        float4 v1 = G4[(size_t)s1 * 32 + f];
        float4 v2 = G4[(size_t)s2 * 32 + f];
        float4 v3 = G4[(size_t)s3 * 32 + f];
        acc.x += v0.x + v1.x + v2.x + v3.x;
        acc.y += v0.y + v1.y + v2.y + v3.y;
        acc.z += v0.z + v1.z + v2.z + v3.z;
        acc.w += v0.w + v1.w + v2.w + v3.w;
    }
    for (int idx = base + slot; idx < e1; idx += 2) {
        int s = col[idx];
        float4 v = G4[(size_t)s * 32 + f];
        acc.x += v.x; acc.y += v.y; acc.z += v.z; acc.w += v.w;
    }
    // combine the two edge slots
    acc.x += __shfl_xor(acc.x, 32);
    acc.y += __shfl_xor(acc.y, 32);
    acc.z += __shfl_xor(acc.z, 32);
    acc.w += __shfl_xor(acc.w, 32);

    if (slot == 0) {
        float4 g = G4[(size_t)n * 32 + f];   // self term (already *dinv[n])
        float di = dinv[n];
        float4 b = bias4[f];
        float4 o;
        o.x = di * (acc.x + g.x) + b.x;
        o.y = di * (acc.y + g.y) + b.y;
        o.z = di * (acc.z + g.z) + b.z;
        o.w = di * (acc.w + g.w) + b.w;
        if (relu) {
            o.x = fmaxf(o.x, 0.f); o.y = fmaxf(o.y, 0.f);
            o.z = fmaxf(o.z, 0.f); o.w = fmaxf(o.w, 0.f);
        }
        Out4[(size_t)n * 32 + f] = o;
    }
}

// ---------------- layer-3 transform: G3 = (X @ W3) * dinv, wave per row --------

__global__ __launch_bounds__(256) void gemm_out2(const float* __restrict__ X,
                                                 const float* __restrict__ W3,
                                                 const float* __restrict__ dinv,
                                                 float* __restrict__ G3, int M) {
    int gtid = blockIdx.x * blockDim.x + threadIdx.x;
    int row = gtid >> 6;
    int lane = threadIdx.x & 63;
    if (row >= M) return;
    const float* xr = X + (size_t)row * 128;
    float x0 = xr[lane], x1 = xr[lane + 64];
    float a0 = x0 * W3[lane * 2 + 0] + x1 * W3[(lane + 64) * 2 + 0];
    float a1 = x0 * W3[lane * 2 + 1] + x1 * W3[(lane + 64) * 2 + 1];
    for (int off = 32; off; off >>= 1) {
        a0 += __shfl_down(a0, off);
        a1 += __shfl_down(a1, off);
    }
    if (lane == 0) {
        float di = dinv[row];
        G3[(size_t)row * 2 + 0] = a0 * di;
        G3[(size_t)row * 2 + 1] = a1 * di;
    }
}

// ---------------- aggregation (2-dim): one thread per node --------------------

__global__ void aggregate2(const float2* __restrict__ G3, const float* __restrict__ dinv,
                           const int* __restrict__ rowptr, const int* __restrict__ col,
                           const float* __restrict__ b3,
                           float2* __restrict__ O3, int N) {
    int n = blockIdx.x * blockDim.x + threadIdx.x;
    if (n >= N) return;
    float s0 = 0.f, s1 = 0.f;
    int e0 = rowptr[n], e1 = rowptr[n + 1];
    int e = e0;
    for (; e + 4 <= e1; e += 4) {
        float2 v0 = G3[col[e]];
        float2 v1 = G3[col[e + 1]];
        float2 v2 = G3[col[e + 2]];
        float2 v3 = G3[col[e + 3]];
        s0 += v0.x + v1.x + v2.x + v3.x;
        s1 += v0.y + v1.y + v2.y + v3.y;
    }
    for (; e < e1; ++e) {
        float2 v = G3[col[e]];
        s0 += v.x; s1 += v.y;
    }
    float2 g = G3[n];
    float di = dinv[n];
    float2 o;
    o.x = di * (s0 + g.x) + b3[0];
    o.y = di * (s1 + g.y) + b3[1];
    O3[n] = o;
}

// ---------------- mean pool over batch segments --------------------------------

__global__ void pool_k(const float* __restrict__ O3, const int* __restrict__ batch,
                       float* __restrict__ pool, int N) {
    __shared__ float ls[64 * 3];
    for (int i = threadIdx.x; i < 192; i += blockDim.x) ls[i] = 0.f;
    __syncthreads();
    int n = blockIdx.x * blockDim.x + threadIdx.x;
    if (n < N) {
        int g = batch[n];
        atomicAdd(&ls[g * 3 + 0], O3[(size_t)n * 2 + 0]);
        atomicAdd(&ls[g * 3 + 1], O3[(size_t)n * 2 + 1]);
        atomicAdd(&ls[g * 3 + 2], 1.0f);
    }
    __syncthreads();
    for (int i = threadIdx.x; i < 192; i += blockDim.x)
        if (ls[i] != 0.f) atomicAdd(&pool[i], ls[i]);
}

__global__ void finalize_k(const float* __restrict__ pool, float* __restrict__ out) {
    int t = threadIdx.x;   // 128 threads: 64 graphs x 2
    if (t < 128) {
        int g = t >> 1, c = t & 1;
        out[t] = pool[g * 3 + c] / fmaxf(pool[g * 3 + 2], 1.0f);
    }
}

// ---------------- launch --------------------------------------------------------

extern "C" void kernel_launch(void* const* d_in, const int* in_sizes, int n_in,
                              void* d_out, int out_size, void* d_ws, size_t ws_size,
                              hipStream_t stream) {
    const float* x   = (const float*)d_in[0];
    const int*  edge = (const int*)d_in[1];
    const int*  batch= (const int*)d_in[2];
    const float* W1  = (const float*)d_in[3];
    const float* b1  = (const float*)d_in[4];
    const float* W2  = (const float*)d_in[5];
    const float* b2  = (const float*)d_in[6];
    const float* W3  = (const float*)d_in[7];
    const float* b3  = (const float*)d_in[8];
    float* out = (float*)d_out;

    int N = in_sizes[0] / 128;
    int E = in_sizes[1] / 2;
    const int* src = edge;
    const int* dst = edge + E;

    char* base = (char*)d_ws;
    size_t off = 0;
    auto alloc = [&](size_t bytes) -> void* {
        void* r = base + off;
        off = (off + bytes + 255) & ~(size_t)255;
        return r;
    };
    float* hA     = (float*)alloc((size_t)N * 128 * 4);
    float* hB     = (float*)alloc((size_t)N * 128 * 4);
    float* dinv   = (float*)alloc((size_t)N * 4);
    int*   cnt    = (int*)alloc((size_t)N * 4);
    int*   incl   = (int*)alloc((size_t)N * 4);
    int*   bsum   = (int*)alloc(1024 * 4);
    int*   boff   = (int*)alloc(1024 * 4);
    int*   rowptr = (int*)alloc((size_t)(N + 1) * 4);
    int*   cursor = (int*)alloc((size_t)(N + 1) * 4);
    int*   col    = (int*)alloc((size_t)E * 4);
    float* h3a    = (float*)alloc((size_t)N * 2 * 4);
    float* h3b    = (float*)alloc((size_t)N * 2 * 4);
    float* pool   = (float*)alloc(64 * 3 * 4);

    hipMemsetAsync(cnt, 0, (size_t)N * 4, stream);
    hipMemsetAsync(pool, 0, 64 * 3 * 4, stream);

    int nb = (N + 255) / 256;
    count_k<<<(E + 255) / 256, 256, 0, stream>>>(dst, cnt, E);
    dinv_k<<<nb, 256, 0, stream>>>(cnt, dinv, N);
    scan1<<<nb, 256, 0, stream>>>(cnt, incl, bsum, N);
    scan2<<<1, 512, 0, stream>>>(bsum, boff, nb);
    scan3<<<nb, 256, 0, stream>>>(incl, boff, rowptr, cursor, N);
    scatter_k<<<(E + 255) / 256, 256, 0, stream>>>(src, dst, cursor, col, E);

    int gb = (N + 127) / 128;
    int ab = (N + 3) / 4;

    // layer 1
    gemm128<<<gb, 256, 0, stream>>>(x, W1, dinv, hA, N);
    aggregate128<<<ab, 256, 0, stream>>>((const float4*)hA, dinv, rowptr, col,
                                         (const float4*)b1, (float4*)hB, 1, N);
    // layer 2
    gemm128<<<gb, 256, 0, stream>>>(hB, W2, dinv, hA, N);
    aggregate128<<<ab, 256, 0, stream>>>((const float4*)hA, dinv, rowptr, col,
                                         (const float4*)b2, (float4*)hB, 1, N);
    // layer 3
    gemm_out2<<<(N * 64 + 255) / 256, 256, 0, stream>>>(hB, W3, dinv, h3a, N);
    aggregate2<<<(N + 255) / 256, 256, 0, stream>>>((const float2*)h3a, dinv, rowptr, col,
                                                    b3, (float2*)h3b, N);
    // pool
    pool_k<<<(N + 255) / 256, 256, 0, stream>>>(h3b, batch, pool, N);
    finalize_k<<<1, 128, 0, stream>>>(pool, out);
}

// Round 4
// 325.562 us; speedup vs baseline: 1.7896x; 1.7896x over previous
//
#include <hip/hip_runtime.h>
#include <hip/hip_fp16.h>

#define EPB 8192        // edges per bin-scatter block
#define SEGCAP 12288    // LDS staging cap for one coarse bucket's edges

// ---------------- generic scan helpers (inclusive chunks + chunk sums) --------

__global__ void scan1(const int* __restrict__ v, int* __restrict__ incl,
                      int* __restrict__ bsum, int n) {
    __shared__ int tmp[256];
    int t = threadIdx.x;
    int gid = blockIdx.x * 256 + t;
    tmp[t] = (gid < n) ? v[gid] : 0;
    __syncthreads();
    for (int off = 1; off < 256; off <<= 1) {
        int x = (t >= off) ? tmp[t - off] : 0;
        __syncthreads();
        tmp[t] += x;
        __syncthreads();
    }
    if (gid < n) incl[gid] = tmp[t];
    if (t == 255) bsum[blockIdx.x] = tmp[255];
}

__global__ void scan2(const int* __restrict__ bsum, int* __restrict__ boff, int nb) {
    __shared__ int tmp[512];
    int t = threadIdx.x;
    int orig = (t < nb) ? bsum[t] : 0;
    tmp[t] = orig;
    __syncthreads();
    for (int off = 1; off < 512; off <<= 1) {
        int x = (t >= off) ? tmp[t - off] : 0;
        __syncthreads();
        tmp[t] += x;
        __syncthreads();
    }
    if (t < nb) boff[t] = tmp[t] - orig;   // exclusive block offset
}

// base[i] = exclusive scan of hist
__global__ void basec_k(const int* __restrict__ incl, const int* __restrict__ boff,
                        const int* __restrict__ hist, int* __restrict__ base, int T) {
    int i = blockIdx.x * 256 + threadIdx.x;
    if (i < T) base[i] = incl[i] + boff[blockIdx.x] - hist[i];
}

// ---------------- pass 0: coarse histogram [bucket][block] --------------------

__global__ __launch_bounds__(256) void hist_k(const int* __restrict__ dst,
                                              int* __restrict__ hist,
                                              int E, int nblk, int nbuk) {
    __shared__ int h[512];
    int t = threadIdx.x;
    for (int i = t; i < nbuk; i += 256) h[i] = 0;
    __syncthreads();
    int start = blockIdx.x * EPB;
    int end = start + EPB; if (end > E) end = E;
    for (int e = start + t; e < end; e += 256) atomicAdd(&h[dst[e] >> 8], 1);
    __syncthreads();
    for (int i = t; i < nbuk; i += 256) hist[i * nblk + blockIdx.x] = h[i];
}

// ---------------- pass 1: bin-scatter with LDS reorder ------------------------
// packed edge: src (bits 0..23) | (dst & 255) << 24

__global__ __launch_bounds__(256) void binscatter_k(const int* __restrict__ src,
                                                    const int* __restrict__ dst,
                                                    const int* __restrict__ base,
                                                    unsigned int* __restrict__ binned,
                                                    int E, int nblk, int nbuk) {
    __shared__ int hloc[512];
    __shared__ int lstart[512];
    __shared__ int stmp[512];
    __shared__ unsigned int pk[EPB];
    __shared__ unsigned short bid[EPB];
    int t = threadIdx.x;
    int blk = blockIdx.x;
    int start = blk * EPB;
    int end = start + EPB; if (end > E) end = E;
    int cntE = end - start;

    for (int i = t; i < nbuk; i += 256) hloc[i] = 0;
    __syncthreads();
    for (int e = start + t; e < end; e += 256) atomicAdd(&hloc[dst[e] >> 8], 1);
    __syncthreads();
    // inclusive scan of hloc (padded to 512) into stmp
    for (int i = t; i < 512; i += 256) stmp[i] = (i < nbuk) ? hloc[i] : 0;
    __syncthreads();
    for (int off = 1; off < 512; off <<= 1) {
        int v0 = (t >= off) ? stmp[t - off] : 0;
        int v1 = stmp[t + 256 - off];
        __syncthreads();
        stmp[t] += v0;
        stmp[t + 256] += v1;
        __syncthreads();
    }
    for (int i = t; i < nbuk; i += 256) {
        int ex = stmp[i] - hloc[i];
        lstart[i] = ex;
        hloc[i] = ex;         // becomes cursor
    }
    __syncthreads();
    // place into LDS reorder buffer
    for (int e = start + t; e < end; e += 256) {
        int d = dst[e];
        int b = d >> 8;
        int r = atomicAdd(&hloc[b], 1);
        pk[r] = (unsigned int)src[e] | ((unsigned int)(d & 255) << 24);
        bid[r] = (unsigned short)b;
    }
    __syncthreads();
    // write bucket-grouped runs to global
    for (int i = t; i < cntE; i += 256) {
        int b = bid[i];
        binned[base[b * nblk + blk] + (i - lstart[b])] = pk[i];
    }
}

// ---------------- pass 2: per-bucket counting sort -> rowptr, dinv, col --------

__global__ __launch_bounds__(256) void group_k(const unsigned int* __restrict__ binned,
                                               const int* __restrict__ base,
                                               int* __restrict__ rowptr,
                                               float* __restrict__ dinv,
                                               int* __restrict__ col,
                                               int nblk, int nbuk, int N, int E) {
    __shared__ int cntL[256];
    __shared__ int sc[256];
    __shared__ int cur[256];
    __shared__ int stage[SEGCAP];
    int b = blockIdx.x, t = threadIdx.x;
    int segstart = base[b * nblk];
    int segend = (b + 1 < nbuk) ? base[(b + 1) * nblk] : E;
    int seglen = segend - segstart;

    cntL[t] = 0;
    __syncthreads();
    for (int i = segstart + t; i < segend; i += 256)
        atomicAdd(&cntL[binned[i] >> 24], 1);
    __syncthreads();
    sc[t] = cntL[t];
    __syncthreads();
    for (int off = 1; off < 256; off <<= 1) {
        int v = (t >= off) ? sc[t - off] : 0;
        __syncthreads();
        sc[t] += v;
        __syncthreads();
    }
    int n = (b << 8) + t;
    if (n < N) {
        rowptr[n + 1] = segstart + sc[t];
        dinv[n] = rsqrtf((float)cntL[t] + 1.0f);
    }
    if (b == 0 && t == 0) rowptr[0] = 0;
    cur[t] = sc[t] - cntL[t];   // exclusive (relative)
    __syncthreads();
    if (seglen <= SEGCAP) {
        for (int i = segstart + t; i < segend; i += 256) {
            unsigned int p = binned[i];
            int r = atomicAdd(&cur[p >> 24], 1);
            stage[r] = (int)(p & 0xFFFFFFu);
        }
        __syncthreads();
        for (int i = t; i < seglen; i += 256) col[segstart + i] = stage[i];
    } else {
        for (int i = segstart + t; i < segend; i += 256) {
            unsigned int p = binned[i];
            int r = atomicAdd(&cur[p >> 24], 1);
            col[segstart + r] = (int)(p & 0xFFFFFFu);
        }
    }
}

// ---------------- GEMM: G = (X @ W) * dinv[row] -> fp16, 128x128 tile ----------

__global__ __launch_bounds__(256) void gemm128(const float* __restrict__ X,
                                               const float* __restrict__ W,
                                               const float* __restrict__ dinv,
                                               __half2* __restrict__ Gh, int M) {
    __shared__ float Xs[32][132];
    __shared__ float Ws[32][128];
    int row0 = blockIdx.x * 128;
    int t = threadIdx.x;
    int tx = t & 15, ty = t >> 4;
    int c0 = tx * 8, r0 = ty * 8;
    float acc[8][8];
#pragma unroll
    for (int i = 0; i < 8; ++i)
#pragma unroll
        for (int j = 0; j < 8; ++j) acc[i][j] = 0.f;

    int lr = t & 7;
    int rbase = t >> 3;

    for (int k0 = 0; k0 < 128; k0 += 32) {
#pragma unroll
        for (int p = 0; p < 4; ++p) {
            int r = rbase + p * 32;
            int rr = row0 + r; if (rr >= M) rr = M - 1;
            const float4 v = *(const float4*)&X[(size_t)rr * 128 + k0 + lr * 4];
            Xs[lr * 4 + 0][r] = v.x;
            Xs[lr * 4 + 1][r] = v.y;
            Xs[lr * 4 + 2][r] = v.z;
            Xs[lr * 4 + 3][r] = v.w;
        }
#pragma unroll
        for (int p = 0; p < 4; ++p) {
            int cc = lr * 4 + p * 32;
            *(float4*)&Ws[rbase][cc] = *(const float4*)&W[(size_t)(k0 + rbase) * 128 + cc];
        }
        __syncthreads();
#pragma unroll
        for (int kk = 0; kk < 32; ++kk) {
            float xa[8], wb[8];
            *(float4*)&xa[0] = *(const float4*)&Xs[kk][r0];
            *(float4*)&xa[4] = *(const float4*)&Xs[kk][r0 + 4];
            *(float4*)&wb[0] = *(const float4*)&Ws[kk][c0];
            *(float4*)&wb[4] = *(const float4*)&Ws[kk][c0 + 4];
#pragma unroll
            for (int i = 0; i < 8; ++i)
#pragma unroll
                for (int j = 0; j < 8; ++j)
                    acc[i][j] += xa[i] * wb[j];
        }
        __syncthreads();
    }
#pragma unroll
    for (int i = 0; i < 8; ++i) {
        int row = row0 + r0 + i;
        if (row < M) {
            float di = dinv[row];
            __half2 hh[4];
#pragma unroll
            for (int k = 0; k < 4; ++k)
                hh[k] = __floats2half2_rn(acc[i][2 * k] * di, acc[i][2 * k + 1] * di);
            ((float4*)Gh)[(size_t)row * 16 + tx] = *(float4*)hh;
        }
    }
}

// ------- aggregation (128-dim, fp16 gather): wave/node, 4 edge slots x 16 lanes

__device__ __forceinline__ void addh8(float* acc, float4 a) {
    const __half2* h = reinterpret_cast<const __half2*>(&a);
#pragma unroll
    for (int j = 0; j < 4; ++j) {
        float2 f2 = __half22float2(h[j]);
        acc[2 * j] += f2.x;
        acc[2 * j + 1] += f2.y;
    }
}

__global__ __launch_bounds__(256) void aggregate128h(const float4* __restrict__ G4,
                                                     const float* __restrict__ dinv,
                                                     const int* __restrict__ rowptr,
                                                     const int* __restrict__ col,
                                                     const float4* __restrict__ bias4,
                                                     float4* __restrict__ Out4,
                                                     int relu, int N) {
    int n = blockIdx.x * 4 + (threadIdx.x >> 6);
    if (n >= N) return;
    int lane = threadIdx.x & 63;
    int f = lane & 15;     // 16B chunk within 256B row
    int slot = lane >> 4;  // 0..3
    int e0 = rowptr[n], e1 = rowptr[n + 1];
    float acc[8];
#pragma unroll
    for (int j = 0; j < 8; ++j) acc[j] = 0.f;

    int base = e0;
    for (; base + 8 <= e1; base += 8) {
        int sA = col[base + slot];
        int sB = col[base + 4 + slot];
        float4 a = G4[(size_t)sA * 16 + f];
        float4 b = G4[(size_t)sB * 16 + f];
        addh8(acc, a);
        addh8(acc, b);
    }
    for (int idx = base + slot; idx < e1; idx += 4) {
        float4 a = G4[(size_t)col[idx] * 16 + f];
        addh8(acc, a);
    }
#pragma unroll
    for (int j = 0; j < 8; ++j) {
        acc[j] += __shfl_xor(acc[j], 16);
        acc[j] += __shfl_xor(acc[j], 32);
    }
    if (slot == 0) {
        float4 g = G4[(size_t)n * 16 + f];   // self (already * dinv[n]), fp16
        float s[8];
        {
            const __half2* h = reinterpret_cast<const __half2*>(&g);
#pragma unroll
            for (int j = 0; j < 4; ++j) {
                float2 f2 = __half22float2(h[j]);
                s[2 * j] = f2.x;
                s[2 * j + 1] = f2.y;
            }
        }
        float di = dinv[n];
        float4 b0 = bias4[f * 2], b1 = bias4[f * 2 + 1];
        float o[8];
        o[0] = di * (acc[0] + s[0]) + b0.x;
        o[1] = di * (acc[1] + s[1]) + b0.y;
        o[2] = di * (acc[2] + s[2]) + b0.z;
        o[3] = di * (acc[3] + s[3]) + b0.w;
        o[4] = di * (acc[4] + s[4]) + b1.x;
        o[5] = di * (acc[5] + s[5]) + b1.y;
        o[6] = di * (acc[6] + s[6]) + b1.z;
        o[7] = di * (acc[7] + s[7]) + b1.w;
        if (relu) {
#pragma unroll
            for (int j = 0; j < 8; ++j) o[j] = fmaxf(o[j], 0.f);
        }
        Out4[(size_t)n * 32 + f * 2]     = make_float4(o[0], o[1], o[2], o[3]);
        Out4[(size_t)n * 32 + f * 2 + 1] = make_float4(o[4], o[5], o[6], o[7]);
    }
}

// ---------------- layer-3 transform: G3 = (X @ W3) * dinv, wave per row --------

__global__ __launch_bounds__(256) void gemm_out2(const float* __restrict__ X,
                                                 const float* __restrict__ W3,
                                                 const float* __restrict__ dinv,
                                                 float* __restrict__ G3, int M) {
    int gtid = blockIdx.x * blockDim.x + threadIdx.x;
    int row = gtid >> 6;
    int lane = threadIdx.x & 63;
    if (row >= M) return;
    const float* xr = X + (size_t)row * 128;
    float x0 = xr[lane], x1 = xr[lane + 64];
    float a0 = x0 * W3[lane * 2 + 0] + x1 * W3[(lane + 64) * 2 + 0];
    float a1 = x0 * W3[lane * 2 + 1] + x1 * W3[(lane + 64) * 2 + 1];
    for (int off = 32; off; off >>= 1) {
        a0 += __shfl_down(a0, off);
        a1 += __shfl_down(a1, off);
    }
    if (lane == 0) {
        float di = dinv[row];
        G3[(size_t)row * 2 + 0] = a0 * di;
        G3[(size_t)row * 2 + 1] = a1 * di;
    }
}

// ---------------- aggregation (2-dim): one thread per node --------------------

__global__ void aggregate2(const float2* __restrict__ G3, const float* __restrict__ dinv,
                           const int* __restrict__ rowptr, const int* __restrict__ col,
                           const float* __restrict__ b3,
                           float2* __restrict__ O3, int N) {
    int n = blockIdx.x * blockDim.x + threadIdx.x;
    if (n >= N) return;
    float s0 = 0.f, s1 = 0.f;
    int e0 = rowptr[n], e1 = rowptr[n + 1];
    int e = e0;
    for (; e + 4 <= e1; e += 4) {
        float2 v0 = G3[col[e]];
        float2 v1 = G3[col[e + 1]];
        float2 v2 = G3[col[e + 2]];
        float2 v3 = G3[col[e + 3]];
        s0 += v0.x + v1.x + v2.x + v3.x;
        s1 += v0.y + v1.y + v2.y + v3.y;
    }
    for (; e < e1; ++e) {
        float2 v = G3[col[e]];
        s0 += v.x; s1 += v.y;
    }
    float2 g = G3[n];
    float di = dinv[n];
    float2 o;
    o.x = di * (s0 + g.x) + b3[0];
    o.y = di * (s1 + g.y) + b3[1];
    O3[n] = o;
}

// ---------------- mean pool over batch segments --------------------------------

__global__ void pool_k(const float* __restrict__ O3, const int* __restrict__ batch,
                       float* __restrict__ pool, int N) {
    __shared__ float ls[64 * 3];
    for (int i = threadIdx.x; i < 192; i += blockDim.x) ls[i] = 0.f;
    __syncthreads();
    int n = blockIdx.x * blockDim.x + threadIdx.x;
    if (n < N) {
        int g = batch[n];
        atomicAdd(&ls[g * 3 + 0], O3[(size_t)n * 2 + 0]);
        atomicAdd(&ls[g * 3 + 1], O3[(size_t)n * 2 + 1]);
        atomicAdd(&ls[g * 3 + 2], 1.0f);
    }
    __syncthreads();
    for (int i = threadIdx.x; i < 192; i += blockDim.x)
        if (ls[i] != 0.f) atomicAdd(&pool[i], ls[i]);
}

__global__ void finalize_k(const float* __restrict__ pool, float* __restrict__ out) {
    int t = threadIdx.x;
    if (t < 128) {
        int g = t >> 1, c = t & 1;
        out[t] = pool[g * 3 + c] / fmaxf(pool[g * 3 + 2], 1.0f);
    }
}

// ---------------- launch --------------------------------------------------------

extern "C" void kernel_launch(void* const* d_in, const int* in_sizes, int n_in,
                              void* d_out, int out_size, void* d_ws, size_t ws_size,
                              hipStream_t stream) {
    const float* x   = (const float*)d_in[0];
    const int*  edge = (const int*)d_in[1];
    const int*  batch= (const int*)d_in[2];
    const float* W1  = (const float*)d_in[3];
    const float* b1  = (const float*)d_in[4];
    const float* W2  = (const float*)d_in[5];
    const float* b2  = (const float*)d_in[6];
    const float* W3  = (const float*)d_in[7];
    const float* b3  = (const float*)d_in[8];
    float* out = (float*)d_out;

    int N = in_sizes[0] / 128;
    int E = in_sizes[1] / 2;
    const int* src = edge;
    const int* dst = edge + E;

    int nblk1 = (E + EPB - 1) / EPB;          // bin-scatter blocks
    int nbuk  = (N + 255) >> 8;               // coarse buckets (<=512)
    int T     = nbuk * nblk1;                 // hist entries
    int nb2   = (T + 255) / 256;              // scan chunks (<=512)

    char* base_ws = (char*)d_ws;
    size_t off = 0;
    auto alloc = [&](size_t bytes) -> void* {
        void* r = base_ws + off;
        off = (off + bytes + 255) & ~(size_t)255;
        return r;
    };
    float*        Hf     = (float*)alloc((size_t)N * 128 * 4);
    __half2*      Gh     = (__half2*)alloc((size_t)N * 64 * 4);
    float*        dinv   = (float*)alloc((size_t)N * 4);
    int*          rowptr = (int*)alloc((size_t)(N + 1) * 4);
    int*          col    = (int*)alloc((size_t)E * 4);
    unsigned int* binned = (unsigned int*)alloc((size_t)E * 4);
    int*          hist   = (int*)alloc((size_t)T * 4);
    int*          incl   = (int*)alloc((size_t)T * 4);
    int*          bsum   = (int*)alloc(1024 * 4);
    int*          boff   = (int*)alloc(1024 * 4);
    int*          basea  = (int*)alloc((size_t)(T + 1) * 4);
    float*        g3     = (float*)alloc((size_t)N * 2 * 4);
    float*        h3b    = (float*)alloc((size_t)N * 2 * 4);
    float*        pool   = (float*)alloc(64 * 3 * 4);

    hipMemsetAsync(pool, 0, 64 * 3 * 4, stream);

    // CSR build via 2-level bucket sort
    hist_k<<<nblk1, 256, 0, stream>>>(dst, hist, E, nblk1, nbuk);
    scan1<<<nb2, 256, 0, stream>>>(hist, incl, bsum, T);
    scan2<<<1, 512, 0, stream>>>(bsum, boff, nb2);
    basec_k<<<nb2, 256, 0, stream>>>(incl, boff, hist, basea, T);
    binscatter_k<<<nblk1, 256, 0, stream>>>(src, dst, basea, binned, E, nblk1, nbuk);
    group_k<<<nbuk, 256, 0, stream>>>(binned, basea, rowptr, dinv, col, nblk1, nbuk, N, E);

    int gb = (N + 127) / 128;
    int ab = (N + 3) / 4;

    // layer 1
    gemm128<<<gb, 256, 0, stream>>>(x, W1, dinv, Gh, N);
    aggregate128h<<<ab, 256, 0, stream>>>((const float4*)Gh, dinv, rowptr, col,
                                          (const float4*)b1, (float4*)Hf, 1, N);
    // layer 2
    gemm128<<<gb, 256, 0, stream>>>(Hf, W2, dinv, Gh, N);
    aggregate128h<<<ab, 256, 0, stream>>>((const float4*)Gh, dinv, rowptr, col,
                                          (const float4*)b2, (float4*)Hf, 1, N);
    // layer 3
    gemm_out2<<<(N * 64 + 255) / 256, 256, 0, stream>>>(Hf, W3, dinv, g3, N);
    aggregate2<<<(N + 255) / 256, 256, 0, stream>>>((const float2*)g3, dinv, rowptr, col,
                                                    b3, (float2*)h3b, N);
    // pool
    pool_k<<<(N + 255) / 256, 256, 0, stream>>>(h3b, batch, pool, N);
    finalize_k<<<1, 128, 0, stream>>>(pool, out);
}

// Round 5
// 321.816 us; speedup vs baseline: 1.8104x; 1.0116x over previous
//
#include <hip/hip_runtime.h>
#include <hip/hip_fp16.h>

#define EPB 8192        // edges per bin-scatter block
#define SEGCAP 12288    // LDS staging cap for one coarse bucket's edges

// ---------------- generic scan helpers ----------------------------------------

__global__ void scan1(const int* __restrict__ v, int* __restrict__ incl,
                      int* __restrict__ bsum, int n) {
    __shared__ int tmp[256];
    int t = threadIdx.x;
    int gid = blockIdx.x * 256 + t;
    tmp[t] = (gid < n) ? v[gid] : 0;
    __syncthreads();
    for (int off = 1; off < 256; off <<= 1) {
        int x = (t >= off) ? tmp[t - off] : 0;
        __syncthreads();
        tmp[t] += x;
        __syncthreads();
    }
    if (gid < n) incl[gid] = tmp[t];
    if (t == 255) bsum[blockIdx.x] = tmp[255];
}

__global__ void scan2(const int* __restrict__ bsum, int* __restrict__ boff, int nb) {
    __shared__ int tmp[512];
    int t = threadIdx.x;
    int orig = (t < nb) ? bsum[t] : 0;
    tmp[t] = orig;
    __syncthreads();
    for (int off = 1; off < 512; off <<= 1) {
        int x = (t >= off) ? tmp[t - off] : 0;
        __syncthreads();
        tmp[t] += x;
        __syncthreads();
    }
    if (t < nb) boff[t] = tmp[t] - orig;
}

__global__ void basec_k(const int* __restrict__ incl, const int* __restrict__ boff,
                        const int* __restrict__ hist, int* __restrict__ base, int T) {
    int i = blockIdx.x * 256 + threadIdx.x;
    if (i < T) base[i] = incl[i] + boff[blockIdx.x] - hist[i];
}

// ---------------- pass 0: coarse histogram [bucket][block] --------------------

__global__ __launch_bounds__(256) void hist_k(const int* __restrict__ dst,
                                              int* __restrict__ hist,
                                              int E, int nblk, int nbuk) {
    __shared__ int h[512];
    int t = threadIdx.x;
    for (int i = t; i < nbuk; i += 256) h[i] = 0;
    __syncthreads();
    int start = blockIdx.x * EPB;
    int end = start + EPB; if (end > E) end = E;
    for (int e = start + t; e < end; e += 256) atomicAdd(&h[dst[e] >> 8], 1);
    __syncthreads();
    for (int i = t; i < nbuk; i += 256) hist[i * nblk + blockIdx.x] = h[i];
}

// ---------------- pass 1: bin-scatter with LDS reorder ------------------------

__global__ __launch_bounds__(256) void binscatter_k(const int* __restrict__ src,
                                                    const int* __restrict__ dst,
                                                    const int* __restrict__ base,
                                                    unsigned int* __restrict__ binned,
                                                    int E, int nblk, int nbuk) {
    __shared__ int hloc[512];
    __shared__ int lstart[512];
    __shared__ int stmp[512];
    __shared__ unsigned int pk[EPB];
    __shared__ unsigned short bid[EPB];
    int t = threadIdx.x;
    int blk = blockIdx.x;
    int start = blk * EPB;
    int end = start + EPB; if (end > E) end = E;
    int cntE = end - start;

    for (int i = t; i < nbuk; i += 256) hloc[i] = 0;
    __syncthreads();
    for (int e = start + t; e < end; e += 256) atomicAdd(&hloc[dst[e] >> 8], 1);
    __syncthreads();
    for (int i = t; i < 512; i += 256) stmp[i] = (i < nbuk) ? hloc[i] : 0;
    __syncthreads();
    for (int off = 1; off < 512; off <<= 1) {
        int v0 = (t >= off) ? stmp[t - off] : 0;
        int v1 = stmp[t + 256 - off];
        __syncthreads();
        stmp[t] += v0;
        stmp[t + 256] += v1;
        __syncthreads();
    }
    for (int i = t; i < nbuk; i += 256) {
        int ex = stmp[i] - hloc[i];
        lstart[i] = ex;
        hloc[i] = ex;
    }
    __syncthreads();
    for (int e = start + t; e < end; e += 256) {
        int d = dst[e];
        int b = d >> 8;
        int r = atomicAdd(&hloc[b], 1);
        pk[r] = (unsigned int)src[e] | ((unsigned int)(d & 255) << 24);
        bid[r] = (unsigned short)b;
    }
    __syncthreads();
    for (int i = t; i < cntE; i += 256) {
        int b = bid[i];
        binned[base[b * nblk + blk] + (i - lstart[b])] = pk[i];
    }
}

// ---------------- pass 2: per-bucket counting sort -> rowptr, dinv, col --------

__global__ __launch_bounds__(256) void group_k(const unsigned int* __restrict__ binned,
                                               const int* __restrict__ base,
                                               int* __restrict__ rowptr,
                                               float* __restrict__ dinv,
                                               int* __restrict__ col,
                                               int nblk, int nbuk, int N, int E) {
    __shared__ int cntL[256];
    __shared__ int sc[256];
    __shared__ int cur[256];
    __shared__ int stage[SEGCAP];
    int b = blockIdx.x, t = threadIdx.x;
    int segstart = base[b * nblk];
    int segend = (b + 1 < nbuk) ? base[(b + 1) * nblk] : E;
    int seglen = segend - segstart;

    cntL[t] = 0;
    __syncthreads();
    for (int i = segstart + t; i < segend; i += 256)
        atomicAdd(&cntL[binned[i] >> 24], 1);
    __syncthreads();
    sc[t] = cntL[t];
    __syncthreads();
    for (int off = 1; off < 256; off <<= 1) {
        int v = (t >= off) ? sc[t - off] : 0;
        __syncthreads();
        sc[t] += v;
        __syncthreads();
    }
    int n = (b << 8) + t;
    if (n < N) {
        rowptr[n + 1] = segstart + sc[t];
        dinv[n] = rsqrtf((float)cntL[t] + 1.0f);
    }
    if (b == 0 && t == 0) rowptr[0] = 0;
    cur[t] = sc[t] - cntL[t];
    __syncthreads();
    if (seglen <= SEGCAP) {
        for (int i = segstart + t; i < segend; i += 256) {
            unsigned int p = binned[i];
            int r = atomicAdd(&cur[p >> 24], 1);
            stage[r] = (int)(p & 0xFFFFFFu);
        }
        __syncthreads();
        for (int i = t; i < seglen; i += 256) col[segstart + i] = stage[i];
    } else {
        for (int i = segstart + t; i < segend; i += 256) {
            unsigned int p = binned[i];
            int r = atomicAdd(&cur[p >> 24], 1);
            col[segstart + r] = (int)(p & 0xFFFFFFu);
        }
    }
}

// ------ GEMM: G = (X @ W) * dinv[row] -> fp16, templated X dtype, X-prefetch ---

template<typename XT>
__global__ __launch_bounds__(256) void gemm128(const XT* __restrict__ X,
                                               const float* __restrict__ W,
                                               const float* __restrict__ dinv,
                                               __half2* __restrict__ Gh, int M) {
    constexpr bool F32 = (sizeof(XT) == 4);
    __shared__ float Xs[32][132];
    __shared__ float Ws[32][128];
    int row0 = blockIdx.x * 128;
    int t = threadIdx.x;
    int tx = t & 15, ty = t >> 4;
    int c0 = tx * 8, r0 = ty * 8;
    float acc[8][8];
#pragma unroll
    for (int i = 0; i < 8; ++i)
#pragma unroll
        for (int j = 0; j < 8; ++j) acc[i][j] = 0.f;

    float4 xr[4];

    auto loadX = [&](int k0) {
        if constexpr (F32) {
#pragma unroll
            for (int p = 0; p < 4; ++p) {
                int r = (t >> 3) + p * 32;
                int rr = row0 + r; if (rr >= M) rr = M - 1;
                xr[p] = *(const float4*)&((const float*)X)[(size_t)rr * 128 + k0 + (t & 7) * 4];
            }
        } else {
#pragma unroll
            for (int p = 0; p < 2; ++p) {
                int r = (t >> 2) + p * 64;
                int rr = row0 + r; if (rr >= M) rr = M - 1;
                xr[p] = ((const float4*)X)[(size_t)rr * 16 + (k0 >> 3) + (t & 3)];
            }
        }
    };
    auto stageX = [&]() {
        if constexpr (F32) {
#pragma unroll
            for (int p = 0; p < 4; ++p) {
                int r = (t >> 3) + p * 32;
                int bse = (t & 7) * 4;
                Xs[bse + 0][r] = xr[p].x;
                Xs[bse + 1][r] = xr[p].y;
                Xs[bse + 2][r] = xr[p].z;
                Xs[bse + 3][r] = xr[p].w;
            }
        } else {
#pragma unroll
            for (int p = 0; p < 2; ++p) {
                int r = (t >> 2) + p * 64;
                int bse = (t & 3) * 8;
                const __half2* h = (const __half2*)&xr[p];
#pragma unroll
                for (int j = 0; j < 4; ++j) {
                    float2 f = __half22float2(h[j]);
                    Xs[bse + 2 * j][r] = f.x;
                    Xs[bse + 2 * j + 1][r] = f.y;
                }
            }
        }
    };

    loadX(0);
    for (int k0 = 0; k0 < 128; k0 += 32) {
        stageX();
#pragma unroll
        for (int p = 0; p < 4; ++p) {
            int cc = (t & 7) * 4 + p * 32;
            *(float4*)&Ws[t >> 3][cc] = *(const float4*)&W[(size_t)(k0 + (t >> 3)) * 128 + cc];
        }
        __syncthreads();
        if (k0 + 32 < 128) loadX(k0 + 32);
#pragma unroll
        for (int kk = 0; kk < 32; ++kk) {
            float xa[8], wb[8];
            *(float4*)&xa[0] = *(const float4*)&Xs[kk][r0];
            *(float4*)&xa[4] = *(const float4*)&Xs[kk][r0 + 4];
            *(float4*)&wb[0] = *(const float4*)&Ws[kk][c0];
            *(float4*)&wb[4] = *(const float4*)&Ws[kk][c0 + 4];
#pragma unroll
            for (int i = 0; i < 8; ++i)
#pragma unroll
                for (int j = 0; j < 8; ++j)
                    acc[i][j] += xa[i] * wb[j];
        }
        __syncthreads();
    }
#pragma unroll
    for (int i = 0; i < 8; ++i) {
        int row = row0 + r0 + i;
        if (row < M) {
            float di = dinv[row];
            __half2 hh[4];
#pragma unroll
            for (int k = 0; k < 4; ++k)
                hh[k] = __floats2half2_rn(acc[i][2 * k] * di, acc[i][2 * k + 1] * di);
            ((float4*)Gh)[(size_t)row * 16 + tx] = *(float4*)hh;
        }
    }
}

// ------- aggregation: fp16 packed accumulate, wave/node, 4 slots x 16 lanes ----

__device__ __forceinline__ void addpk(__half2* acc, float4 v) {
    const __half2* h = reinterpret_cast<const __half2*>(&v);
#pragma unroll
    for (int j = 0; j < 4; ++j) acc[j] = __hadd2(acc[j], h[j]);
}

__global__ __launch_bounds__(256) void aggregate128h(const float4* __restrict__ G4,
                                                     const float* __restrict__ dinv,
                                                     const int* __restrict__ rowptr,
                                                     const int* __restrict__ col,
                                                     const float4* __restrict__ bias4,
                                                     float4* __restrict__ OutH,
                                                     int relu, int N) {
    int n = blockIdx.x * 4 + (threadIdx.x >> 6);
    if (n >= N) return;
    int lane = threadIdx.x & 63;
    int f = lane & 15;     // 16B chunk (8 halves) within 256B row
    int slot = lane >> 4;  // 0..3
    int e0 = rowptr[n], e1 = rowptr[n + 1];
    __half2 acc[4];
#pragma unroll
    for (int j = 0; j < 4; ++j) acc[j] = __float2half2_rn(0.f);

    int base = e0;
    for (; base + 16 <= e1; base += 16) {
        int s0 = col[base + slot];
        int s1 = col[base + 4 + slot];
        int s2 = col[base + 8 + slot];
        int s3 = col[base + 12 + slot];
        float4 v0 = G4[s0 * 16 + f];
        float4 v1 = G4[s1 * 16 + f];
        float4 v2 = G4[s2 * 16 + f];
        float4 v3 = G4[s3 * 16 + f];
        addpk(acc, v0); addpk(acc, v1); addpk(acc, v2); addpk(acc, v3);
    }
    for (int idx = base + slot; idx < e1; idx += 4) {
        float4 v = G4[col[idx] * 16 + f];
        addpk(acc, v);
    }
    float a[8];
#pragma unroll
    for (int j = 0; j < 4; ++j) {
        float2 fp = __half22float2(acc[j]);
        a[2 * j] = fp.x;
        a[2 * j + 1] = fp.y;
    }
#pragma unroll
    for (int j = 0; j < 8; ++j) {
        a[j] += __shfl_xor(a[j], 16);
        a[j] += __shfl_xor(a[j], 32);
    }
    if (slot == 0) {
        float4 g = G4[n * 16 + f];
        float s[8];
        {
            const __half2* h = reinterpret_cast<const __half2*>(&g);
#pragma unroll
            for (int j = 0; j < 4; ++j) {
                float2 fp = __half22float2(h[j]);
                s[2 * j] = fp.x;
                s[2 * j + 1] = fp.y;
            }
        }
        float di = dinv[n];
        float4 b0 = bias4[f * 2], b1 = bias4[f * 2 + 1];
        float o[8];
        o[0] = di * (a[0] + s[0]) + b0.x;
        o[1] = di * (a[1] + s[1]) + b0.y;
        o[2] = di * (a[2] + s[2]) + b0.z;
        o[3] = di * (a[3] + s[3]) + b0.w;
        o[4] = di * (a[4] + s[4]) + b1.x;
        o[5] = di * (a[5] + s[5]) + b1.y;
        o[6] = di * (a[6] + s[6]) + b1.z;
        o[7] = di * (a[7] + s[7]) + b1.w;
        if (relu) {
#pragma unroll
            for (int j = 0; j < 8; ++j) o[j] = fmaxf(o[j], 0.f);
        }
        __half2 hh[4];
#pragma unroll
        for (int j = 0; j < 4; ++j) hh[j] = __floats2half2_rn(o[2 * j], o[2 * j + 1]);
        OutH[n * 16 + f] = *(float4*)hh;
    }
}

// -------- layer-3 transform (fp16 in): G3 = (X @ W3) * dinv, wave per row ------

__global__ __launch_bounds__(256) void gemm_out2h(const __half2* __restrict__ Xh,
                                                  const float* __restrict__ W3,
                                                  const float* __restrict__ dinv,
                                                  float* __restrict__ G3, int M) {
    int gtid = blockIdx.x * blockDim.x + threadIdx.x;
    int row = gtid >> 6;
    int lane = threadIdx.x & 63;
    if (row >= M) return;
    __half2 h = Xh[(size_t)row * 64 + lane];
    float2 f = __half22float2(h);
    int c = lane * 2;
    float a0 = f.x * W3[c * 2 + 0] + f.y * W3[(c + 1) * 2 + 0];
    float a1 = f.x * W3[c * 2 + 1] + f.y * W3[(c + 1) * 2 + 1];
    for (int off = 32; off; off >>= 1) {
        a0 += __shfl_down(a0, off);
        a1 += __shfl_down(a1, off);
    }
    if (lane == 0) {
        float di = dinv[row];
        G3[(size_t)row * 2 + 0] = a0 * di;
        G3[(size_t)row * 2 + 1] = a1 * di;
    }
}

// ---------------- aggregation (2-dim): one thread per node --------------------

__global__ void aggregate2(const float2* __restrict__ G3, const float* __restrict__ dinv,
                           const int* __restrict__ rowptr, const int* __restrict__ col,
                           const float* __restrict__ b3,
                           float2* __restrict__ O3, int N) {
    int n = blockIdx.x * blockDim.x + threadIdx.x;
    if (n >= N) return;
    float s0 = 0.f, s1 = 0.f;
    int e0 = rowptr[n], e1 = rowptr[n + 1];
    int e = e0;
    for (; e + 4 <= e1; e += 4) {
        float2 v0 = G3[col[e]];
        float2 v1 = G3[col[e + 1]];
        float2 v2 = G3[col[e + 2]];
        float2 v3 = G3[col[e + 3]];
        s0 += v0.x + v1.x + v2.x + v3.x;
        s1 += v0.y + v1.y + v2.y + v3.y;
    }
    for (; e < e1; ++e) {
        float2 v = G3[col[e]];
        s0 += v.x; s1 += v.y;
    }
    float2 g = G3[n];
    float di = dinv[n];
    float2 o;
    o.x = di * (s0 + g.x) + b3[0];
    o.y = di * (s1 + g.y) + b3[1];
    O3[n] = o;
}

// ---------------- mean pool over batch segments --------------------------------

__global__ void pool_k(const float* __restrict__ O3, const int* __restrict__ batch,
                       float* __restrict__ pool, int N) {
    __shared__ float ls[64 * 3];
    for (int i = threadIdx.x; i < 192; i += blockDim.x) ls[i] = 0.f;
    __syncthreads();
    int n = blockIdx.x * blockDim.x + threadIdx.x;
    if (n < N) {
        int g = batch[n];
        atomicAdd(&ls[g * 3 + 0], O3[(size_t)n * 2 + 0]);
        atomicAdd(&ls[g * 3 + 1], O3[(size_t)n * 2 + 1]);
        atomicAdd(&ls[g * 3 + 2], 1.0f);
    }
    __syncthreads();
    for (int i = threadIdx.x; i < 192; i += blockDim.x)
        if (ls[i] != 0.f) atomicAdd(&pool[i], ls[i]);
}

__global__ void finalize_k(const float* __restrict__ pool, float* __restrict__ out) {
    int t = threadIdx.x;
    if (t < 128) {
        int g = t >> 1, c = t & 1;
        out[t] = pool[g * 3 + c] / fmaxf(pool[g * 3 + 2], 1.0f);
    }
}

// ---------------- launch --------------------------------------------------------

extern "C" void kernel_launch(void* const* d_in, const int* in_sizes, int n_in,
                              void* d_out, int out_size, void* d_ws, size_t ws_size,
                              hipStream_t stream) {
    const float* x   = (const float*)d_in[0];
    const int*  edge = (const int*)d_in[1];
    const int*  batch= (const int*)d_in[2];
    const float* W1  = (const float*)d_in[3];
    const float* b1  = (const float*)d_in[4];
    const float* W2  = (const float*)d_in[5];
    const float* b2  = (const float*)d_in[6];
    const float* W3  = (const float*)d_in[7];
    const float* b3  = (const float*)d_in[8];
    float* out = (float*)d_out;

    int N = in_sizes[0] / 128;
    int E = in_sizes[1] / 2;
    const int* src = edge;
    const int* dst = edge + E;

    int nblk1 = (E + EPB - 1) / EPB;
    int nbuk  = (N + 255) >> 8;
    int T     = nbuk * nblk1;
    int nb2   = (T + 255) / 256;

    char* base_ws = (char*)d_ws;
    size_t off = 0;
    auto alloc = [&](size_t bytes) -> void* {
        void* r = base_ws + off;
        off = (off + bytes + 255) & ~(size_t)255;
        return r;
    };
    __half2*      GhA    = (__half2*)alloc((size_t)N * 64 * 4);
    __half2*      GhB    = (__half2*)alloc((size_t)N * 64 * 4);
    float*        dinv   = (float*)alloc((size_t)N * 4);
    int*          rowptr = (int*)alloc((size_t)(N + 1) * 4);
    int*          col    = (int*)alloc((size_t)E * 4);
    unsigned int* binned = (unsigned int*)alloc((size_t)E * 4);
    int*          hist   = (int*)alloc((size_t)T * 4);
    int*          incl   = (int*)alloc((size_t)T * 4);
    int*          bsum   = (int*)alloc(1024 * 4);
    int*          boff   = (int*)alloc(1024 * 4);
    int*          basea  = (int*)alloc((size_t)(T + 1) * 4);
    float*        g3     = (float*)alloc((size_t)N * 2 * 4);
    float*        h3b    = (float*)alloc((size_t)N * 2 * 4);
    float*        pool   = (float*)alloc(64 * 3 * 4);

    hipMemsetAsync(pool, 0, 64 * 3 * 4, stream);

    // CSR build via 2-level bucket sort
    hist_k<<<nblk1, 256, 0, stream>>>(dst, hist, E, nblk1, nbuk);
    scan1<<<nb2, 256, 0, stream>>>(hist, incl, bsum, T);
    scan2<<<1, 512, 0, stream>>>(bsum, boff, nb2);
    basec_k<<<nb2, 256, 0, stream>>>(incl, boff, hist, basea, T);
    binscatter_k<<<nblk1, 256, 0, stream>>>(src, dst, basea, binned, E, nblk1, nbuk);
    group_k<<<nbuk, 256, 0, stream>>>(binned, basea, rowptr, dinv, col, nblk1, nbuk, N, E);

    int gb = (N + 127) / 128;
    int ab = (N + 3) / 4;

    // layer 1 (f32 input)
    gemm128<float><<<gb, 256, 0, stream>>>(x, W1, dinv, GhA, N);
    aggregate128h<<<ab, 256, 0, stream>>>((const float4*)GhA, dinv, rowptr, col,
                                          (const float4*)b1, (float4*)GhB, 1, N);
    // layer 2 (fp16 input)
    gemm128<__half><<<gb, 256, 0, stream>>>((const __half*)GhB, W2, dinv, GhA, N);
    aggregate128h<<<ab, 256, 0, stream>>>((const float4*)GhA, dinv, rowptr, col,
                                          (const float4*)b2, (float4*)GhB, 1, N);
    // layer 3
    gemm_out2h<<<(N * 64 + 255) / 256, 256, 0, stream>>>(GhB, W3, dinv, g3, N);
    aggregate2<<<(N + 255) / 256, 256, 0, stream>>>((const float2*)g3, dinv, rowptr, col,
                                                    b3, (float2*)h3b, N);
    // pool
    pool_k<<<(N + 255) / 256, 256, 0, stream>>>(h3b, batch, pool, N);
    finalize_k<<<1, 128, 0, stream>>>(pool, out);
}

// Round 6
// 257.288 us; speedup vs baseline: 2.2645x; 1.2508x over previous
//
#include <hip/hip_runtime.h>
#include <hip/hip_fp16.h>

#define EPB 8192        // edges per bin-scatter block
#define SEGCAP 12288    // LDS staging cap for one coarse bucket's edges

typedef __attribute__((ext_vector_type(8))) _Float16 half8;
typedef __attribute__((ext_vector_type(4))) float f32x4;

// ---------------- generic scan helpers ----------------------------------------

__global__ void scan1(const int* __restrict__ v, int* __restrict__ incl,
                      int* __restrict__ bsum, int n) {
    __shared__ int tmp[256];
    int t = threadIdx.x;
    int gid = blockIdx.x * 256 + t;
    tmp[t] = (gid < n) ? v[gid] : 0;
    __syncthreads();
    for (int off = 1; off < 256; off <<= 1) {
        int x = (t >= off) ? tmp[t - off] : 0;
        __syncthreads();
        tmp[t] += x;
        __syncthreads();
    }
    if (gid < n) incl[gid] = tmp[t];
    if (t == 255) bsum[blockIdx.x] = tmp[255];
}

__global__ void scan2(const int* __restrict__ bsum, int* __restrict__ boff, int nb) {
    __shared__ int tmp[512];
    int t = threadIdx.x;
    int orig = (t < nb) ? bsum[t] : 0;
    tmp[t] = orig;
    __syncthreads();
    for (int off = 1; off < 512; off <<= 1) {
        int x = (t >= off) ? tmp[t - off] : 0;
        __syncthreads();
        tmp[t] += x;
        __syncthreads();
    }
    if (t < nb) boff[t] = tmp[t] - orig;
}

__global__ void basec_k(const int* __restrict__ incl, const int* __restrict__ boff,
                        const int* __restrict__ hist, int* __restrict__ base, int T) {
    int i = blockIdx.x * 256 + threadIdx.x;
    if (i < T) base[i] = incl[i] + boff[blockIdx.x] - hist[i];
}

// ---------------- pass 0: coarse histogram [bucket][block] --------------------

__global__ __launch_bounds__(256) void hist_k(const int* __restrict__ dst,
                                              int* __restrict__ hist,
                                              int E, int nblk, int nbuk) {
    __shared__ int h[512];
    int t = threadIdx.x;
    for (int i = t; i < nbuk; i += 256) h[i] = 0;
    __syncthreads();
    int start = blockIdx.x * EPB;
    int end = start + EPB; if (end > E) end = E;
    for (int e = start + t; e < end; e += 256) atomicAdd(&h[dst[e] >> 8], 1);
    __syncthreads();
    for (int i = t; i < nbuk; i += 256) hist[i * nblk + blockIdx.x] = h[i];
}

// ---------------- pass 1: bin-scatter with LDS reorder ------------------------

__global__ __launch_bounds__(256) void binscatter_k(const int* __restrict__ src,
                                                    const int* __restrict__ dst,
                                                    const int* __restrict__ base,
                                                    unsigned int* __restrict__ binned,
                                                    int E, int nblk, int nbuk) {
    __shared__ int hloc[512];
    __shared__ int lstart[512];
    __shared__ int stmp[512];
    __shared__ unsigned int pk[EPB];
    __shared__ unsigned short bid[EPB];
    int t = threadIdx.x;
    int blk = blockIdx.x;
    int start = blk * EPB;
    int end = start + EPB; if (end > E) end = E;
    int cntE = end - start;

    for (int i = t; i < nbuk; i += 256) hloc[i] = 0;
    __syncthreads();
    for (int e = start + t; e < end; e += 256) atomicAdd(&hloc[dst[e] >> 8], 1);
    __syncthreads();
    for (int i = t; i < 512; i += 256) stmp[i] = (i < nbuk) ? hloc[i] : 0;
    __syncthreads();
    for (int off = 1; off < 512; off <<= 1) {
        int v0 = (t >= off) ? stmp[t - off] : 0;
        int v1 = stmp[t + 256 - off];
        __syncthreads();
        stmp[t] += v0;
        stmp[t + 256] += v1;
        __syncthreads();
    }
    for (int i = t; i < nbuk; i += 256) {
        int ex = stmp[i] - hloc[i];
        lstart[i] = ex;
        hloc[i] = ex;
    }
    __syncthreads();
    for (int e = start + t; e < end; e += 256) {
        int d = dst[e];
        int b = d >> 8;
        int r = atomicAdd(&hloc[b], 1);
        pk[r] = (unsigned int)src[e] | ((unsigned int)(d & 255) << 24);
        bid[r] = (unsigned short)b;
    }
    __syncthreads();
    for (int i = t; i < cntE; i += 256) {
        int b = bid[i];
        binned[base[b * nblk + blk] + (i - lstart[b])] = pk[i];
    }
}

// ---------------- pass 2: per-bucket counting sort -> rowptr, dinv, col --------

__global__ __launch_bounds__(256) void group_k(const unsigned int* __restrict__ binned,
                                               const int* __restrict__ base,
                                               int* __restrict__ rowptr,
                                               float* __restrict__ dinv,
                                               int* __restrict__ col,
                                               int nblk, int nbuk, int N, int E) {
    __shared__ int cntL[256];
    __shared__ int sc[256];
    __shared__ int cur[256];
    __shared__ int stage[SEGCAP];
    int b = blockIdx.x, t = threadIdx.x;
    int segstart = base[b * nblk];
    int segend = (b + 1 < nbuk) ? base[(b + 1) * nblk] : E;
    int seglen = segend - segstart;

    cntL[t] = 0;
    __syncthreads();
    for (int i = segstart + t; i < segend; i += 256)
        atomicAdd(&cntL[binned[i] >> 24], 1);
    __syncthreads();
    sc[t] = cntL[t];
    __syncthreads();
    for (int off = 1; off < 256; off <<= 1) {
        int v = (t >= off) ? sc[t - off] : 0;
        __syncthreads();
        sc[t] += v;
        __syncthreads();
    }
    int n = (b << 8) + t;
    if (n < N) {
        rowptr[n + 1] = segstart + sc[t];
        dinv[n] = rsqrtf((float)cntL[t] + 1.0f);
    }
    if (b == 0 && t == 0) rowptr[0] = 0;
    cur[t] = sc[t] - cntL[t];
    __syncthreads();
    if (seglen <= SEGCAP) {
        for (int i = segstart + t; i < segend; i += 256) {
            unsigned int p = binned[i];
            int r = atomicAdd(&cur[p >> 24], 1);
            stage[r] = (int)(p & 0xFFFFFFu);
        }
        __syncthreads();
        for (int i = t; i < seglen; i += 256) col[segstart + i] = stage[i];
    } else {
        for (int i = segstart + t; i < segend; i += 256) {
            unsigned int p = binned[i];
            int r = atomicAdd(&cur[p >> 24], 1);
            col[segstart + r] = (int)(p & 0xFFFFFFu);
        }
    }
}

// ------- pack W (f32 [128][128]) into fp16 MFMA B-fragment order --------------
// Wp[((q*8+ct)*64 + lane)*8 + j] = W[q*32 + (lane>>4)*8 + j][ct*16 + (lane&15)]

__global__ __launch_bounds__(256) void packW_k(const float* __restrict__ W,
                                               _Float16* __restrict__ Wp) {
    int t = blockIdx.x * 256 + threadIdx.x;   // 0..2047
    int lane = t & 63, qct = t >> 6;
    int q = qct >> 3, ct = qct & 7;
    int krow = q * 32 + (lane >> 4) * 8;
    int c = ct * 16 + (lane & 15);
#pragma unroll
    for (int j = 0; j < 8; ++j)
        Wp[(size_t)t * 8 + j] = (_Float16)W[(krow + j) * 128 + c];
}

// ------- MFMA GEMM: G = (X @ W) * dinv[row] -> fp16 ---------------------------
// block: 4 waves x 16-row stripes (64 rows); W fragments staged in LDS (32KB)

template<typename XT>
__global__ __launch_bounds__(256) void gemm_mfma(const XT* __restrict__ X,
                                                 const _Float16* __restrict__ Wp,
                                                 const float* __restrict__ dinv,
                                                 _Float16* __restrict__ Gh, int M) {
    constexpr bool F32 = (sizeof(XT) == 4);
    __shared__ _Float16 Wl[16384];           // 32 KB: 32 frags x 64 lanes x 8
    int t = threadIdx.x;
    for (int i = t; i < 2048; i += 256)
        *(float4*)&Wl[(size_t)i * 8] = ((const float4*)Wp)[i];

    int wid = t >> 6, lane = t & 63;
    int row0 = blockIdx.x * 64 + wid * 16;
    int arow = row0 + (lane & 15); if (arow >= M) arow = M - 1;
    int kgrp = (lane >> 4) * 8;

    half8 a[4];
    if constexpr (F32) {
#pragma unroll
        for (int q = 0; q < 4; ++q) {
            const float* p = (const float*)X + (size_t)arow * 128 + q * 32 + kgrp;
            float4 u = *(const float4*)p;
            float4 v = *(const float4*)(p + 4);
            half8 h;
            h[0] = (_Float16)u.x; h[1] = (_Float16)u.y;
            h[2] = (_Float16)u.z; h[3] = (_Float16)u.w;
            h[4] = (_Float16)v.x; h[5] = (_Float16)v.y;
            h[6] = (_Float16)v.z; h[7] = (_Float16)v.w;
            a[q] = h;
        }
    } else {
#pragma unroll
        for (int q = 0; q < 4; ++q)
            a[q] = *(const half8*)((const _Float16*)X + (size_t)arow * 128 + q * 32 + kgrp);
    }
    __syncthreads();

    f32x4 acc[8];
#pragma unroll
    for (int ct = 0; ct < 8; ++ct) acc[ct] = (f32x4){0.f, 0.f, 0.f, 0.f};

#pragma unroll
    for (int q = 0; q < 4; ++q) {
#pragma unroll
        for (int ct = 0; ct < 8; ++ct) {
            half8 b = *(const half8*)&Wl[(size_t)((q * 8 + ct) * 64 + lane) * 8];
            acc[ct] = __builtin_amdgcn_mfma_f32_16x16x32_f16(a[q], b, acc[ct], 0, 0, 0);
        }
    }

    // epilogue: lane holds C[(lane>>4)*4 + reg][lane&15] of each 16x16 tile
    int rbase = row0 + (lane >> 4) * 4;
#pragma unroll
    for (int reg = 0; reg < 4; ++reg) {
        int r = rbase + reg;
        if (r < M) {
            float di = dinv[r];
#pragma unroll
            for (int ct = 0; ct < 8; ++ct)
                Gh[(size_t)r * 128 + ct * 16 + (lane & 15)] = (_Float16)(acc[ct][reg] * di);
        }
    }
}

// ------- aggregation: fp16 packed accumulate, wave/node, 4 slots x 16 lanes ----

__device__ __forceinline__ void addpk(__half2* acc, float4 v) {
    const __half2* h = reinterpret_cast<const __half2*>(&v);
#pragma unroll
    for (int j = 0; j < 4; ++j) acc[j] = __hadd2(acc[j], h[j]);
}

__global__ __launch_bounds__(256) void aggregate128h(const float4* __restrict__ G4,
                                                     const float* __restrict__ dinv,
                                                     const int* __restrict__ rowptr,
                                                     const int* __restrict__ col,
                                                     const float4* __restrict__ bias4,
                                                     float4* __restrict__ OutH,
                                                     int relu, int N) {
    int n = blockIdx.x * 4 + (threadIdx.x >> 6);
    if (n >= N) return;
    int lane = threadIdx.x & 63;
    int f = lane & 15;
    int slot = lane >> 4;
    int e0 = rowptr[n], e1 = rowptr[n + 1];
    __half2 acc[4];
#pragma unroll
    for (int j = 0; j < 4; ++j) acc[j] = __float2half2_rn(0.f);

    int base = e0;
    for (; base + 16 <= e1; base += 16) {
        int s0 = col[base + slot];
        int s1 = col[base + 4 + slot];
        int s2 = col[base + 8 + slot];
        int s3 = col[base + 12 + slot];
        float4 v0 = G4[s0 * 16 + f];
        float4 v1 = G4[s1 * 16 + f];
        float4 v2 = G4[s2 * 16 + f];
        float4 v3 = G4[s3 * 16 + f];
        addpk(acc, v0); addpk(acc, v1); addpk(acc, v2); addpk(acc, v3);
    }
    for (int idx = base + slot; idx < e1; idx += 4) {
        float4 v = G4[col[idx] * 16 + f];
        addpk(acc, v);
    }
    float a[8];
#pragma unroll
    for (int j = 0; j < 4; ++j) {
        float2 fp = __half22float2(acc[j]);
        a[2 * j] = fp.x;
        a[2 * j + 1] = fp.y;
    }
#pragma unroll
    for (int j = 0; j < 8; ++j) {
        a[j] += __shfl_xor(a[j], 16);
        a[j] += __shfl_xor(a[j], 32);
    }
    if (slot == 0) {
        float4 g = G4[n * 16 + f];
        float s[8];
        {
            const __half2* h = reinterpret_cast<const __half2*>(&g);
#pragma unroll
            for (int j = 0; j < 4; ++j) {
                float2 fp = __half22float2(h[j]);
                s[2 * j] = fp.x;
                s[2 * j + 1] = fp.y;
            }
        }
        float di = dinv[n];
        float4 b0 = bias4[f * 2], b1 = bias4[f * 2 + 1];
        float o[8];
        o[0] = di * (a[0] + s[0]) + b0.x;
        o[1] = di * (a[1] + s[1]) + b0.y;
        o[2] = di * (a[2] + s[2]) + b0.z;
        o[3] = di * (a[3] + s[3]) + b0.w;
        o[4] = di * (a[4] + s[4]) + b1.x;
        o[5] = di * (a[5] + s[5]) + b1.y;
        o[6] = di * (a[6] + s[6]) + b1.z;
        o[7] = di * (a[7] + s[7]) + b1.w;
        if (relu) {
#pragma unroll
            for (int j = 0; j < 8; ++j) o[j] = fmaxf(o[j], 0.f);
        }
        __half2 hh[4];
#pragma unroll
        for (int j = 0; j < 4; ++j) hh[j] = __floats2half2_rn(o[2 * j], o[2 * j + 1]);
        OutH[n * 16 + f] = *(float4*)hh;
    }
}

// -------- layer-3 transform (fp16 in): G3 = (X @ W3) * dinv, wave per row ------

__global__ __launch_bounds__(256) void gemm_out2h(const __half2* __restrict__ Xh,
                                                  const float* __restrict__ W3,
                                                  const float* __restrict__ dinv,
                                                  float* __restrict__ G3, int M) {
    int gtid = blockIdx.x * blockDim.x + threadIdx.x;
    int row = gtid >> 6;
    int lane = threadIdx.x & 63;
    if (row >= M) return;
    __half2 h = Xh[(size_t)row * 64 + lane];
    float2 f = __half22float2(h);
    int c = lane * 2;
    float a0 = f.x * W3[c * 2 + 0] + f.y * W3[(c + 1) * 2 + 0];
    float a1 = f.x * W3[c * 2 + 1] + f.y * W3[(c + 1) * 2 + 1];
    for (int off = 32; off; off >>= 1) {
        a0 += __shfl_down(a0, off);
        a1 += __shfl_down(a1, off);
    }
    if (lane == 0) {
        float di = dinv[row];
        G3[(size_t)row * 2 + 0] = a0 * di;
        G3[(size_t)row * 2 + 1] = a1 * di;
    }
}

// ---------------- aggregation (2-dim): one thread per node --------------------

__global__ void aggregate2(const float2* __restrict__ G3, const float* __restrict__ dinv,
                           const int* __restrict__ rowptr, const int* __restrict__ col,
                           const float* __restrict__ b3,
                           float2* __restrict__ O3, int N) {
    int n = blockIdx.x * blockDim.x + threadIdx.x;
    if (n >= N) return;
    float s0 = 0.f, s1 = 0.f;
    int e0 = rowptr[n], e1 = rowptr[n + 1];
    int e = e0;
    for (; e + 4 <= e1; e += 4) {
        float2 v0 = G3[col[e]];
        float2 v1 = G3[col[e + 1]];
        float2 v2 = G3[col[e + 2]];
        float2 v3 = G3[col[e + 3]];
        s0 += v0.x + v1.x + v2.x + v3.x;
        s1 += v0.y + v1.y + v2.y + v3.y;
    }
    for (; e < e1; ++e) {
        float2 v = G3[col[e]];
        s0 += v.x; s1 += v.y;
    }
    float2 g = G3[n];
    float di = dinv[n];
    float2 o;
    o.x = di * (s0 + g.x) + b3[0];
    o.y = di * (s1 + g.y) + b3[1];
    O3[n] = o;
}

// ---------------- mean pool over batch segments --------------------------------

__global__ void pool_k(const float* __restrict__ O3, const int* __restrict__ batch,
                       float* __restrict__ pool, int N) {
    __shared__ float ls[64 * 3];
    for (int i = threadIdx.x; i < 192; i += blockDim.x) ls[i] = 0.f;
    __syncthreads();
    int n = blockIdx.x * blockDim.x + threadIdx.x;
    if (n < N) {
        int g = batch[n];
        atomicAdd(&ls[g * 3 + 0], O3[(size_t)n * 2 + 0]);
        atomicAdd(&ls[g * 3 + 1], O3[(size_t)n * 2 + 1]);
        atomicAdd(&ls[g * 3 + 2], 1.0f);
    }
    __syncthreads();
    for (int i = threadIdx.x; i < 192; i += blockDim.x)
        if (ls[i] != 0.f) atomicAdd(&pool[i], ls[i]);
}

__global__ void finalize_k(const float* __restrict__ pool, float* __restrict__ out) {
    int t = threadIdx.x;
    if (t < 128) {
        int g = t >> 1, c = t & 1;
        out[t] = pool[g * 3 + c] / fmaxf(pool[g * 3 + 2], 1.0f);
    }
}

// ---------------- launch --------------------------------------------------------

extern "C" void kernel_launch(void* const* d_in, const int* in_sizes, int n_in,
                              void* d_out, int out_size, void* d_ws, size_t ws_size,
                              hipStream_t stream) {
    const float* x   = (const float*)d_in[0];
    const int*  edge = (const int*)d_in[1];
    const int*  batch= (const int*)d_in[2];
    const float* W1  = (const float*)d_in[3];
    const float* b1  = (const float*)d_in[4];
    const float* W2  = (const float*)d_in[5];
    const float* b2  = (const float*)d_in[6];
    const float* W3  = (const float*)d_in[7];
    const float* b3  = (const float*)d_in[8];
    float* out = (float*)d_out;

    int N = in_sizes[0] / 128;
    int E = in_sizes[1] / 2;
    const int* src = edge;
    const int* dst = edge + E;

    int nblk1 = (E + EPB - 1) / EPB;
    int nbuk  = (N + 255) >> 8;
    int T     = nbuk * nblk1;
    int nb2   = (T + 255) / 256;

    char* base_ws = (char*)d_ws;
    size_t off = 0;
    auto alloc = [&](size_t bytes) -> void* {
        void* r = base_ws + off;
        off = (off + bytes + 255) & ~(size_t)255;
        return r;
    };
    _Float16*     GhA    = (_Float16*)alloc((size_t)N * 128 * 2);
    _Float16*     GhB    = (_Float16*)alloc((size_t)N * 128 * 2);
    _Float16*     Wp1    = (_Float16*)alloc(16384 * 2);
    _Float16*     Wp2    = (_Float16*)alloc(16384 * 2);
    float*        dinv   = (float*)alloc((size_t)N * 4);
    int*          rowptr = (int*)alloc((size_t)(N + 1) * 4);
    int*          col    = (int*)alloc((size_t)E * 4);
    unsigned int* binned = (unsigned int*)alloc((size_t)E * 4);
    int*          hist   = (int*)alloc((size_t)T * 4);
    int*          incl   = (int*)alloc((size_t)T * 4);
    int*          bsum   = (int*)alloc(1024 * 4);
    int*          boff   = (int*)alloc(1024 * 4);
    int*          basea  = (int*)alloc((size_t)(T + 1) * 4);
    float*        g3     = (float*)alloc((size_t)N * 2 * 4);
    float*        h3b    = (float*)alloc((size_t)N * 2 * 4);
    float*        pool   = (float*)alloc(64 * 3 * 4);

    hipMemsetAsync(pool, 0, 64 * 3 * 4, stream);

    // W pre-packing for MFMA (independent of CSR)
    packW_k<<<8, 256, 0, stream>>>(W1, Wp1);
    packW_k<<<8, 256, 0, stream>>>(W2, Wp2);

    // CSR build via 2-level bucket sort
    hist_k<<<nblk1, 256, 0, stream>>>(dst, hist, E, nblk1, nbuk);
    scan1<<<nb2, 256, 0, stream>>>(hist, incl, bsum, T);
    scan2<<<1, 512, 0, stream>>>(bsum, boff, nb2);
    basec_k<<<nb2, 256, 0, stream>>>(incl, boff, hist, basea, T);
    binscatter_k<<<nblk1, 256, 0, stream>>>(src, dst, basea, binned, E, nblk1, nbuk);
    group_k<<<nbuk, 256, 0, stream>>>(binned, basea, rowptr, dinv, col, nblk1, nbuk, N, E);

    int gb = (N + 63) / 64;
    int ab = (N + 3) / 4;

    // layer 1 (f32 input, MFMA)
    gemm_mfma<float><<<gb, 256, 0, stream>>>(x, Wp1, dinv, GhA, N);
    aggregate128h<<<ab, 256, 0, stream>>>((const float4*)GhA, dinv, rowptr, col,
                                          (const float4*)b1, (float4*)GhB, 1, N);
    // layer 2 (fp16 input, MFMA)
    gemm_mfma<_Float16><<<gb, 256, 0, stream>>>(GhB, Wp2, dinv, GhA, N);
    aggregate128h<<<ab, 256, 0, stream>>>((const float4*)GhA, dinv, rowptr, col,
                                          (const float4*)b2, (float4*)GhB, 1, N);
    // layer 3
    gemm_out2h<<<(N * 64 + 255) / 256, 256, 0, stream>>>((const __half2*)GhB, W3, dinv, g3, N);
    aggregate2<<<(N + 255) / 256, 256, 0, stream>>>((const float2*)g3, dinv, rowptr, col,
                                                    b3, (float2*)h3b, N);
    // pool
    pool_k<<<(N + 255) / 256, 256, 0, stream>>>(h3b, batch, pool, N);
    finalize_k<<<1, 128, 0, stream>>>(pool, out);
}